// Round 9
// baseline (252.627 us; speedup 1.0000x reference)
//
#include <hip/hip_runtime.h>
#include <hip/hip_bf16.h>
#include <cstdint>

#define NPTS (2048 * 192)          // 393216 points
#define TBL  (1u << 19)            // hash table size per level
#define TMASK (TBL - 1u)
#define PBLOCKS (NPTS / 256)       // 1536 blocks per level
#define ENC_BLOCKS (PBLOCKS * 16)  // 24576
#define PREP_BLOCKS 11             // 44 frags * 64 lanes / 256
#define MLP_BLOCKS 768             // 768 blocks * 4 waves * 8 groups * 16 pts
#define P2 2654435761u
#define P3 805459861u

// geomspace(16, 2048, 16).astype(int)
__constant__ float LVLS[16] = {16.f, 22.f, 30.f, 42.f, 58.f, 80.f, 111.f, 153.f,
                               212.f, 294.f, 406.f, 561.f, 776.f, 1072.f, 1482.f, 2048.f};

#if __has_builtin(__builtin_amdgcn_sinf)
#define SIN_REV(x) __builtin_amdgcn_sinf(x)   // sin(2*pi*x)
#else
#define SIN_REV(x) __sinf(6.28318530717958647f * (x))
#endif

typedef __fp16 h16x2 __attribute__((ext_vector_type(2)));
typedef __fp16 h16x4 __attribute__((ext_vector_type(4)));   // K=16 MFMA A/B frag (2 VGPRs)
typedef float  f32x4 __attribute__((ext_vector_type(4)));   // MFMA C/D frag

// Legacy K=16 f16 MFMA. Layout (canonical CDNA):
//   A[m][k]: m=lane&15, k=(lane>>4)*4+j      B[k][n]: n=lane&15, k=(lane>>4)*4+j
//   D[row][col]: col=lane&15, row=(lane>>4)*4+reg
// KEY: D row index == B k index (quad*4 + {reg|j}) -> layer-to-layer transition
// is LANE-LOCAL (relu+pack only, no shuffles). Round-7 post-mortem: the 56
// ds_bpermute/group transpose chains were k_mlp's real bottleneck.
#if __has_builtin(__builtin_amdgcn_mfma_f32_16x16x16_f16)
#define MFMA16(A, B, C) __builtin_amdgcn_mfma_f32_16x16x16_f16(A, B, C, 0, 0, 0)
#else
#define MFMA16(A, B, C) __builtin_amdgcn_mfma_f32_16x16x16f16(A, B, C, 0, 0, 0)
#endif

// single-instruction f32x2 -> packed f16x2 (RTZ)
__device__ __forceinline__ uint32_t pkh(float a, float b) {
#if __has_builtin(__builtin_amdgcn_cvt_pkrtz)
    union { h16x2 h; uint32_t u; } t;
    t.h = __builtin_amdgcn_cvt_pkrtz(a, b);
    return t.u;
#else
    union { __fp16 e[2]; uint32_t u; } t;
    t.e[0] = (__fp16)a; t.e[1] = (__fp16)b;
    return t.u;
#endif
}

// ---------------------------------------------------------------------------
// Kernel 1: hash-grid encode + (tail blocks) weight-fragment prepack.
// Encode unchanged structurally (at ~90% of the TCC request-rate floor,
// ~30M L2 requests / 128 channels / 2.4GHz ~= 105us). XCD-affine level
// mapping keeps one 4MB table per XCD L2. Feats now packed f16 (pkrtz).
//
// Prepack: 44 A-fragments for the K=16 MFMA chain, f16, one uint2/lane.
// Frag ids: L1(dW1,32->64): mt*2+kt (0-7); L2(dW2,64->16): 8+kt (8-11);
// L3(cW1+cb1 row43,44->64): 12+mt*3+kt (12-23); L4(cW2): 24+mt*4+kt (24-39);
// L5(cW3,64->3): 40+kt (40-43).  A[m][k] = W[k0+q*4+j][m0+col].
// ---------------------------------------------------------------------------
__global__ __launch_bounds__(256) void k_encode(const float* __restrict__ x,
                                                const float* __restrict__ tables,
                                                uint32_t* __restrict__ feats,
                                                const float* __restrict__ dW1,
                                                const float* __restrict__ dW2,
                                                const float* __restrict__ cW1,
                                                const float* __restrict__ cb1,
                                                const float* __restrict__ cW2,
                                                const float* __restrict__ cW3,
                                                uint2* __restrict__ wfrags)
{
    if (blockIdx.x >= ENC_BLOCKS) {
        int t = (blockIdx.x - ENC_BLOCKS) * 256 + threadIdx.x;
        if (t >= 44 * 64) return;
        int frag = t >> 6, lane = t & 63;
        int q = lane >> 4, col = lane & 15;
        const float* W; const float* bfold = nullptr;
        int OUT, Kact, Mact, k0, m0;
        if (frag < 8)       { int i = frag;      W = dW1; OUT = 64; Kact = 32; Mact = 64;
                              k0 = (i & 1) * 16; m0 = (i >> 1) * 16; }
        else if (frag < 12) { W = dW2; OUT = 16; Kact = 64; Mact = 16; k0 = (frag - 8) * 16; m0 = 0; }
        else if (frag < 24) { int i = frag - 12; W = cW1; OUT = 64; Kact = 43; Mact = 64;
                              k0 = (i % 3) * 16; m0 = (i / 3) * 16; bfold = cb1; }
        else if (frag < 40) { int i = frag - 24; W = cW2; OUT = 64; Kact = 64; Mact = 64;
                              k0 = (i & 3) * 16; m0 = (i >> 2) * 16; }
        else                { W = cW3; OUT = 3;  Kact = 64; Mact = 3;  k0 = (frag - 40) * 16; m0 = 0; }
        int m = m0 + col;
        union { __fp16 e[4]; uint2 u; } o;
#pragma unroll
        for (int j = 0; j < 4; ++j) {
            int k = k0 + q * 4 + j;
            float v = 0.f;
            if (m < Mact) {
                if (k < Kact) v = W[(size_t)k * OUT + m];
                else if (bfold && k == Kact) v = bfold[m];
            }
            o.e[j] = (__fp16)v;   // RNE
        }
        wfrags[t] = o.u;
        return;
    }

    // ---- XCD-affine decode of (level, point-block) ----
    int xs   = blockIdx.x & 7;          // XCD slot
    int i    = blockIdx.x >> 3;         // 0..3071
    int half = i / PBLOCKS;             // 0: levels 0-7, 1: levels 8-15
    int pb   = i - half * PBLOCKS;      // point-block 0..1535
    int lvl  = xs + (half << 3);
    int p    = pb * 256 + threadIdx.x;

    size_t p3 = (size_t)p * 3;
    float x0 = x[p3 + 0] + 0.5f;
    float x1 = x[p3 + 1] + 0.5f;
    float x2 = x[p3 + 2] + 0.5f;
    size_t oidx = (size_t)lvl * NPTS + p;

    bool m = (x0 > 0.f) && (x0 < 1.f) && (x1 > 0.f) && (x1 < 1.f) &&
             (x2 > 0.f) && (x2 < 1.f);
    if (!m) { feats[oidx] = 0u; return; }   // masked: features never used

    float s  = LVLS[lvl];
    float px = x0 * s, py = x1 * s, pz = x2 * s;
    float flx = floorf(px), fly = floorf(py), flz = floorf(pz);
    float frx = px - flx,   fry = py - fly,   frz = pz - flz;
    int ix = (int)flx, iy = (int)fly, iz = (int)flz;
    uint32_t ux = (uint32_t)ix, uy = (uint32_t)iy, uz = (uint32_t)iz;

    uint32_t base[4];
    base[0] = (uy * P2) ^ (uz * P3);
    base[1] = ((uy + 1u) * P2) ^ (uz * P3);
    base[2] = (uy * P2) ^ ((uz + 1u) * P3);
    base[3] = ((uy + 1u) * P2) ^ ((uz + 1u) * P3);

    const float2* tb = (const float2*)tables + (size_t)lvl * TBL;

    float2 v[8];
    if ((ix & 1) == 0) {
        // even ix: corners (ix, ix+1) live at (h, h^1) -> one aligned float4
        const float4* tb4 = (const float4*)tb;
#pragma unroll
        for (int cc = 0; cc < 4; ++cc) {
            uint32_t h0 = (base[cc] ^ ux) & TMASK;
            float4 qv = tb4[h0 >> 1];
            bool hi = (h0 & 1u) != 0u;
            float2 e0 = hi ? make_float2(qv.z, qv.w) : make_float2(qv.x, qv.y);
            float2 e1 = hi ? make_float2(qv.x, qv.y) : make_float2(qv.z, qv.w);
            v[(cc << 1)]     = e0;
            v[(cc << 1) | 1] = e1;
        }
    } else {
        uint32_t h[8];
#pragma unroll
        for (int c = 0; c < 8; ++c)
            h[c] = (base[c >> 1] ^ (ux + (uint32_t)(c & 1))) & TMASK;
#pragma unroll
        for (int c = 0; c < 8; ++c) v[c] = tb[h[c]];
    }

    float f0 = 0.f, f1 = 0.f;
#pragma unroll
    for (int c = 0; c < 8; ++c) {
        float w = ((c & 1)        ? frx : 1.f - frx)
                * (((c >> 1) & 1) ? fry : 1.f - fry)
                * (((c >> 2) & 1) ? frz : 1.f - frz);
        f0 += w * v[c].x;
        f1 += w * v[c].y;
    }
    feats[oidx] = pkh(f0, f1);
}

// av-vector row value for rows 16..47. One transcendental per row
// (cos(x) = sin(x + 0.25 rev)).
__device__ __forceinline__ float pe_val(int r, float rx, float ry, float rz)
{
    int t = r - 19;
    int d = t >> 3;
    int s = t & 7;
    float comp = (d == 0) ? rx : ((d == 1) ? ry : rz);
    float a = ldexpf(comp, s & 3) + ((s >= 4) ? 0.25f : 0.0f);
    float v = SIN_REV(a);
    if (r == 16) v = rx;
    if (r == 17) v = ry;
    if (r == 18) v = rz;
    if (r == 43) v = 1.0f;
    if (r > 43)  v = 0.0f;
    return v;
}

// ---------------------------------------------------------------------------
// Kernel 2: MLP stack on K=16 f16 matrix cores. Wave = 16 points per group
// (N dim), 8 groups/wave. Weights in A (prepacked), activations in B.
// D->B transitions are lane-local (relu + v_cvt_pkrtz) -- no cross-lane ops.
// ---------------------------------------------------------------------------
__global__ __launch_bounds__(256) void k_mlp(const uint32_t* __restrict__ feats,
                                             const uint2* __restrict__ wfrags,
                                             const float* __restrict__ x,
                                             const float* __restrict__ rdir,
                                             const float* __restrict__ db1,
                                             const float* __restrict__ db2,
                                             const float* __restrict__ cb2,
                                             const float* __restrict__ cb3,
                                             float* __restrict__ out)
{
    int lane = threadIdx.x & 63;
    int q = lane >> 4, col = lane & 15;
    int wgid = blockIdx.x * 4 + (threadIdx.x >> 6);

    union Fr { h16x4 v; uint2 u; uint32_t d[2]; };

    // ---- persistent weight fragments: 44 coalesced dwordx2 loads ----
    Fr A1[4][2], A2[4], A3[4][3], A4[4][4], A5[4];
#pragma unroll
    for (int mt = 0; mt < 4; ++mt)
#pragma unroll
        for (int kt = 0; kt < 2; ++kt) A1[mt][kt].u = wfrags[(mt * 2 + kt) * 64 + lane];
#pragma unroll
    for (int kt = 0; kt < 4; ++kt) A2[kt].u = wfrags[(8 + kt) * 64 + lane];
#pragma unroll
    for (int mt = 0; mt < 4; ++mt)
#pragma unroll
        for (int kt = 0; kt < 3; ++kt) A3[mt][kt].u = wfrags[(12 + mt * 3 + kt) * 64 + lane];
#pragma unroll
    for (int mt = 0; mt < 4; ++mt)
#pragma unroll
        for (int kt = 0; kt < 4; ++kt) A4[mt][kt].u = wfrags[(24 + mt * 4 + kt) * 64 + lane];
#pragma unroll
    for (int kt = 0; kt < 4; ++kt) A5[kt].u = wfrags[(40 + kt) * 64 + lane];

    for (int it = 0; it < 8; ++it) {
        int g = (wgid * 8 + it) << 4;        // point base of this 16-group
        int pt = g + col;
        size_t pt3 = (size_t)pt * 3;

        // ---- feats B-frags: k-tile kt, element j -> f16-pair 8kt + 2q + (j>>1)
        Fr Bf0, Bf1;
        Bf0.d[0] = feats[(size_t)(2 * q + 0) * NPTS + pt];
        Bf0.d[1] = feats[(size_t)(2 * q + 1) * NPTS + pt];
        Bf1.d[0] = feats[(size_t)(8 + 2 * q + 0) * NPTS + pt];
        Bf1.d[1] = feats[(size_t)(8 + 2 * q + 1) * NPTS + pt];

        // ---- L1: feats(32) -> h1(64), bias, relu
        f32x4 D1[4];
#pragma unroll
        for (int mt = 0; mt < 4; ++mt) {
            const float4 bb = *(const float4*)&db1[mt * 16 + q * 4];
            f32x4 c; c[0] = bb.x; c[1] = bb.y; c[2] = bb.z; c[3] = bb.w;
            c = MFMA16(A1[mt][0].v, Bf0.v, c);
            D1[mt] = MFMA16(A1[mt][1].v, Bf1.v, c);
        }
        Fr B2[4];
#pragma unroll
        for (int mt = 0; mt < 4; ++mt) {
            B2[mt].d[0] = pkh(fmaxf(D1[mt][0], 0.f), fmaxf(D1[mt][1], 0.f));
            B2[mt].d[1] = pkh(fmaxf(D1[mt][2], 0.f), fmaxf(D1[mt][3], 0.f));
        }

        // ---- L2: h1(64) -> log_sigma(16), bias, linear
        f32x4 Dls;
        {
            const float4 bb = *(const float4*)&db2[q * 4];
            f32x4 c; c[0] = bb.x; c[1] = bb.y; c[2] = bb.z; c[3] = bb.w;
#pragma unroll
            for (int kt = 0; kt < 4; ++kt) c = MFMA16(A2[kt].v, B2[kt].v, c);
            Dls = c;
        }

        // ---- av B-frags: k-tile0 = ls (lane-local from Dls), tiles 1-2 = PE
        float rx = rdir[pt3 + 0], ry = rdir[pt3 + 1], rz = rdir[pt3 + 2];
        Fr B3[3];
        B3[0].d[0] = pkh(Dls[0], Dls[1]);
        B3[0].d[1] = pkh(Dls[2], Dls[3]);
        {
            int b = 16 + 4 * q;
            B3[1].d[0] = pkh(pe_val(b + 0, rx, ry, rz), pe_val(b + 1, rx, ry, rz));
            B3[1].d[1] = pkh(pe_val(b + 2, rx, ry, rz), pe_val(b + 3, rx, ry, rz));
        }
        {
            int b = 32 + 4 * q;
            B3[2].d[0] = pkh(pe_val(b + 0, rx, ry, rz), pe_val(b + 1, rx, ry, rz));
            B3[2].d[1] = pkh(pe_val(b + 2, rx, ry, rz), pe_val(b + 3, rx, ry, rz));
        }

        // ---- L3: av(43+1) -> c1(64), bias folded via row 43, relu
        Fr B4[4];
#pragma unroll
        for (int mt = 0; mt < 4; ++mt) {
            f32x4 c = {0.f, 0.f, 0.f, 0.f};
#pragma unroll
            for (int kt = 0; kt < 3; ++kt) c = MFMA16(A3[mt][kt].v, B3[kt].v, c);
            B4[mt].d[0] = pkh(fmaxf(c[0], 0.f), fmaxf(c[1], 0.f));
            B4[mt].d[1] = pkh(fmaxf(c[2], 0.f), fmaxf(c[3], 0.f));
        }

        // ---- L4: c1(64) -> c2(64), bias, relu
        Fr B5[4];
#pragma unroll
        for (int mt = 0; mt < 4; ++mt) {
            const float4 bb = *(const float4*)&cb2[mt * 16 + q * 4];
            f32x4 c; c[0] = bb.x; c[1] = bb.y; c[2] = bb.z; c[3] = bb.w;
#pragma unroll
            for (int kt = 0; kt < 4; ++kt) c = MFMA16(A4[mt][kt].v, B4[kt].v, c);
            B5[mt].d[0] = pkh(fmaxf(c[0], 0.f), fmaxf(c[1], 0.f));
            B5[mt].d[1] = pkh(fmaxf(c[2], 0.f), fmaxf(c[3], 0.f));
        }

        // ---- L5: c2(64) -> color(3), bias, sigmoid
        f32x4 c5 = {0.f, 0.f, 0.f, 0.f};
        if (q == 0) { c5[0] = cb3[0]; c5[1] = cb3[1]; c5[2] = cb3[2]; }
#pragma unroll
        for (int kt = 0; kt < 4; ++kt) c5 = MFMA16(A5[kt].v, B5[kt].v, c5);

        // ---- outputs: color rows 0-2 and sigma row 0 live in quad 0
        if (q == 0) {
            float xfx = x[pt3 + 0] + 0.5f;
            float xfy = x[pt3 + 1] + 0.5f;
            float xfz = x[pt3 + 2] + 0.5f;
            bool m = (xfx > 0.f) && (xfx < 1.f) && (xfy > 0.f) && (xfy < 1.f) &&
                     (xfz > 0.f) && (xfz < 1.f);
            out[pt3 + 0] = m ? 1.f / (1.f + __expf(-c5[0])) : 0.f;
            out[pt3 + 1] = m ? 1.f / (1.f + __expf(-c5[1])) : 0.f;
            out[pt3 + 2] = m ? 1.f / (1.f + __expf(-c5[2])) : 0.f;
            out[(size_t)3 * NPTS + pt] = m ? __expf(Dls[0]) : 0.f;
        }
    }
}

extern "C" void kernel_launch(void* const* d_in, const int* in_sizes, int n_in,
                              void* d_out, int out_size, void* d_ws, size_t ws_size,
                              hipStream_t stream) {
    const float* x      = (const float*)d_in[0];
    const float* rdir   = (const float*)d_in[1];
    const float* tables = (const float*)d_in[2];
    const float* dW1 = (const float*)d_in[3];
    const float* db1 = (const float*)d_in[4];
    const float* dW2 = (const float*)d_in[5];
    const float* db2 = (const float*)d_in[6];
    const float* cW1 = (const float*)d_in[7];
    const float* cb1 = (const float*)d_in[8];
    const float* cW2 = (const float*)d_in[9];
    const float* cb2 = (const float*)d_in[10];
    const float* cW3 = (const float*)d_in[11];
    const float* cb3 = (const float*)d_in[12];
    float* out = (float*)d_out;

    uint2*    wfrags = (uint2*)d_ws;                        // 22.5 KB
    uint32_t* feats  = (uint32_t*)((char*)d_ws + 32768);    // 16*NPTS*4 B

    k_encode<<<ENC_BLOCKS + PREP_BLOCKS, 256, 0, stream>>>(
        x, tables, feats, dW1, dW2, cW1, cb1, cW2, cW3, wfrags);
    k_mlp<<<MLP_BLOCKS, 256, 0, stream>>>(feats, wfrags, x, rdir,
                                          db1, db2, cb2, cb3, out);
}